// Round 7
// baseline (287.060 us; speedup 1.0000x reference)
//
#include <hip/hip_runtime.h>
#include <hip/hip_bf16.h>

#define NN 50000
#define NE 800000
#define FD 128
#define L1CAP 16000
#define L2CAP 512
#define BCAP 64      // per-slot bucket capacity; mean in-degree 16, P(>64) ~ 1e-18

// ---------------- frontier construction ----------------

__global__ void k_mark(const int* __restrict__ states, const int* __restrict__ actions,
                       int* __restrict__ flagL2, int* __restrict__ flagL1,
                       int* __restrict__ nodeL2, int* __restrict__ cnt) {
    int i = blockIdx.x * blockDim.x + threadIdx.x;
    if (i == 0) cnt[1] = 257;   // fixed layer-2 slot count
    if (i < 257) {
        int n = (i < 256) ? states[i] : actions[0];
        flagL2[n] = i + 1;      // duplicate states race: one slot wins; losing slots
        flagL1[n] = 1;          // are never read (readout maps through flagL2)
        nodeL2[i] = n;
    }
}

// Scan all edges for layer-2 targets; bucket hits directly (fixed stride).
__global__ __launch_bounds__(256) void k_scan_targets(
        const int4* __restrict__ esrc4, const int4* __restrict__ edst4,
        const int* __restrict__ flagL2, int* __restrict__ flagL1,
        int* __restrict__ cur2, int* __restrict__ bsrc2) {
    int t = blockIdx.x * blockDim.x + threadIdx.x;
    if (t >= NE / 4) return;
    int4 d4 = edst4[t];
    int4 s4 = esrc4[t];
    int f[4] = {flagL2[d4.x], flagL2[d4.y], flagL2[d4.z], flagL2[d4.w]};
    int s[4] = {s4.x, s4.y, s4.z, s4.w};
#pragma unroll
    for (int j = 0; j < 4; ++j) {
        if (f[j] > 0) {
            int slot = f[j] - 1;
            int pos = atomicAdd(&cur2[slot], 1);
            if (pos < BCAP) bsrc2[slot * BCAP + pos] = s[j];  // raw node id
            flagL1[s[j]] = 1;   // idempotent mark
        }
    }
}

// Compact L1 frontier: flagL1[n] -> slot+1, nodeL1[slot] = n.
__global__ __launch_bounds__(256) void k_assign(
        int* __restrict__ flagL1, int* __restrict__ nodeL1, int* __restrict__ cnt) {
    int n = blockIdx.x * blockDim.x + threadIdx.x;
    bool pred = (n < NN) && (flagL1[n] != 0);
    unsigned long long mask = __ballot(pred);
    if (mask == 0) return;
    int lane = threadIdx.x & 63;
    int prefix = __popcll(mask & ((1ull << lane) - 1));
    int fl = __ffsll((long long)mask) - 1;
    int base = 0;
    if (lane == fl) base = atomicAdd(&cnt[0], __popcll(mask));
    base = __shfl(base, fl, 64);
    if (pred) {
        int slot = base + prefix;
        if (slot < L1CAP) { flagL1[n] = slot + 1; nodeL1[slot] = n; }
        else flagL1[n] = 0;     // overflow safety (never hit with this graph)
    }
}

// Scan all edges for L1-frontier destinations; bucket hits (fixed stride).
__global__ __launch_bounds__(256) void k_scan_l1(
        const int4* __restrict__ esrc4, const int4* __restrict__ edst4,
        const int* __restrict__ flagL1, int* __restrict__ cur1,
        int* __restrict__ bsrc1) {
    int t = blockIdx.x * blockDim.x + threadIdx.x;
    if (t >= NE / 4) return;
    int4 d4 = edst4[t];
    int4 s4 = esrc4[t];
    int f[4] = {flagL1[d4.x], flagL1[d4.y], flagL1[d4.z], flagL1[d4.w]};
    int s[4] = {s4.x, s4.y, s4.z, s4.w};
#pragma unroll
    for (int j = 0; j < 4; ++j) {
        if (f[j] > 0) {
            int slot = f[j] - 1;
            int pos = atomicAdd(&cur1[slot], 1);
            if (pos < BCAP) bsrc1[slot * BCAP + pos] = s[j];  // x row id
        }
    }
}

// ---------------- aggregation gather (1 wave per slot, zero atomics) --------

__global__ __launch_bounds__(256) void k_gather(
        const int* __restrict__ cur, const int* __restrict__ bsrc,
        const int* __restrict__ srcMap, const int* __restrict__ cntPtr,
        const float* __restrict__ srcMat, float* __restrict__ aggc) {
    int w = (blockIdx.x * blockDim.x + threadIdx.x) >> 6;
    int lane = threadIdx.x & 63;
    if (w >= *cntPtr) return;
    int n = cur[w]; if (n > BCAP) n = BCAP;
    const int* bp = bsrc + (size_t)w * BCAP;
    float ax = 0.0f, ay = 0.0f;
    int e = 0;
    for (; e + 1 < n; e += 2) {       // 2-edge unroll for load ILP
        int r0 = bp[e], r1 = bp[e + 1];
        if (srcMap) { r0 = srcMap[r0] - 1; r1 = srcMap[r1] - 1; }
        float2 v0 = ((const float2*)(srcMat + (size_t)r0 * FD))[lane];
        float2 v1 = ((const float2*)(srcMat + (size_t)r1 * FD))[lane];
        ax += v0.x + v1.x; ay += v0.y + v1.y;
    }
    if (e < n) {
        int r = bp[e];
        if (srcMap) r = srcMap[r] - 1;
        float2 v = ((const float2*)(srcMat + (size_t)r * FD))[lane];
        ax += v.x; ay += v.y;
    }
    float2 outv = {ax, ay};
    ((float2*)(aggc + (size_t)w * FD))[lane] = outv;
}

// ---------------- fused SAGE layer GEMM ----------------
// out[slot][o] = relu( self·Wself[o] + (agg/max(deg,1))·Wneigh[o] + b[o] )
// block = 256 thr (4 waves), tile 32 slots x 128 outs, micro 2x8.
// Staging is latency-batched: phase A resolves indices (one short chain),
// phase B issues 8 independent float4 loads per thread back-to-back.
// Previous per-slot sequential staging chains = 59 us/dispatch wall.
// LDS row stride 132 -> broadcast reads hit banks {0,4,...}: conflict-free.

#define GSLOTS 32
#define LDSTR 132

__global__ __launch_bounds__(256) void k_gemm(
        const float* __restrict__ selfMat, const int* __restrict__ selfIdx,
        const int* __restrict__ selfMap, const float* __restrict__ aggc,
        const int* __restrict__ cur,
        const float* __restrict__ Wself, const float* __restrict__ Wneigh,
        const float* __restrict__ bias, float* __restrict__ outc,
        const int* __restrict__ cntPtr) {
    __shared__ float sx[GSLOTS][LDSTR];
    __shared__ float sa[GSLOTS][LDSTR];
    __shared__ int   srowL[GSLOTS];
    __shared__ float sinvL[GSLOTS];
    int cnt = *cntPtr;
    int base = blockIdx.x * GSLOTS;
    if (base >= cnt) return;
    int tid = threadIdx.x;

    // phase A: resolve slot indices & degree factors (parallel, one chain)
    if (tid < GSLOTS) {
        int slot = base + tid;
        bool live = slot < cnt;
        int sidx = live ? selfIdx[slot] : 0;
        int srow = selfMap ? (selfMap[sidx] - 1) : sidx;
        if (srow < 0) srow = 0;                    // dead-slot safety
        srowL[tid] = srow;
        int n = live ? cur[slot] : 0;
        sinvL[tid] = 1.0f / fmaxf((float)n, 1.0f);
    }
    __syncthreads();

    // phase B: batched vector staging. 256 thr x float4 = 8 rows/pass, 4 passes.
    {
        int c4 = tid & 31;          // float4 column 0..31
        int r0 = tid >> 5;          // row 0..7
        float4 rx[4], ra[4];
#pragma unroll
        for (int i = 0; i < 4; ++i) {
            int r = r0 + 8 * i;
            int sr = srowL[r];
            rx[i] = ((const float4*)(selfMat + (size_t)sr * FD))[c4];
            ra[i] = ((const float4*)(aggc + (size_t)(base + r) * FD))[c4];
        }
#pragma unroll
        for (int i = 0; i < 4; ++i) {
            int r = r0 + 8 * i;
            float inv = sinvL[r];
            *(float4*)&sx[r][c4 * 4] = rx[i];
            float4 a = ra[i];
            a.x *= inv; a.y *= inv; a.z *= inv; a.w *= inv;
            *(float4*)&sa[r][c4 * 4] = a;
        }
    }
    __syncthreads();

    int og = tid & 15;       // 16 out-groups -> o = og + 16*j
    int sg = tid >> 4;       // 16 slot-groups -> s = sg + 16*i
    float acc[2][8];
#pragma unroll
    for (int i = 0; i < 2; ++i)
#pragma unroll
        for (int j = 0; j < 8; ++j) acc[i][j] = 0.0f;

    for (int k = 0; k < FD; k += 4) {
        float4 xv[2], av[2];
#pragma unroll
        for (int i = 0; i < 2; ++i) {
            int s = sg + 16 * i;
            xv[i] = *(const float4*)&sx[s][k];
            av[i] = *(const float4*)&sa[s][k];
        }
#pragma unroll
        for (int j = 0; j < 8; ++j) {
            int o = og + 16 * j;
            float4 ws = *(const float4*)&Wself[(size_t)o * FD + k];
            float4 wn = *(const float4*)&Wneigh[(size_t)o * FD + k];
#pragma unroll
            for (int i = 0; i < 2; ++i) {
                acc[i][j] += xv[i].x * ws.x + xv[i].y * ws.y + xv[i].z * ws.z + xv[i].w * ws.w
                           + av[i].x * wn.x + av[i].y * wn.y + av[i].z * wn.z + av[i].w * wn.w;
            }
        }
    }

#pragma unroll
    for (int j = 0; j < 8; ++j) {
        int o = og + 16 * j;
        float b = bias[o];
#pragma unroll
        for (int i = 0; i < 2; ++i) {
            int slot = base + sg + 16 * i;
            outc[(size_t)slot * FD + o] = fmaxf(acc[i][j] + b, 0.0f);
        }
    }
}

// ---------------- readout ----------------
// Transposed: thread owns one feature, register fmax chain, zero atomics.

__global__ __launch_bounds__(256) void k_readout(
        const float* __restrict__ h2c, const int* __restrict__ flagL2,
        const int* __restrict__ states, const int* __restrict__ actions,
        const float* __restrict__ Wfc, const float* __restrict__ bfc,
        float* __restrict__ out) {
    __shared__ int slotS[256];
    __shared__ float halfmax[2][FD];
    __shared__ float red[256];
    int tid = threadIdx.x;
    slotS[tid] = flagL2[states[tid]] - 1;
    __syncthreads();

    int f = tid & (FD - 1);
    int half = tid >> 7;             // 0 or 1
    float m = 0.0f;                  // h2 >= 0 post-ReLU, 0 is identity for max
#pragma unroll 8
    for (int s = half * 128; s < half * 128 + 128; ++s) {
        m = fmaxf(m, h2c[(size_t)slotS[s] * FD + f]);
    }
    halfmax[half][f] = m;
    __syncthreads();

    float v = 0.0f;
    if (tid < FD) {
        int aslot = flagL2[actions[0]] - 1;
        float mm = fmaxf(halfmax[0][tid], halfmax[1][tid]);
        float av = h2c[(size_t)aslot * FD + tid];
        v = mm * Wfc[tid] + av * Wfc[FD + tid];
    }
    red[tid] = v;
    __syncthreads();
    for (int s = 128; s > 0; s >>= 1) {
        if (tid < s) red[tid] += red[tid + s];
        __syncthreads();
    }
    if (tid == 0) out[0] = red[0] + bfc[0];
}

// ---------------- launch ----------------

extern "C" void kernel_launch(void* const* d_in, const int* in_sizes, int n_in,
                              void* d_out, int out_size, void* d_ws, size_t ws_size,
                              hipStream_t stream) {
    const float* x    = (const float*)d_in[0];
    const int* esrc   = (const int*)d_in[1];
    const int* edst   = (const int*)d_in[2];
    const int* states = (const int*)d_in[3];
    const int* acts   = (const int*)d_in[4];
    const float* W1s  = (const float*)d_in[5];
    const float* W1n  = (const float*)d_in[6];
    const float* b1   = (const float*)d_in[7];
    const float* W2s  = (const float*)d_in[8];
    const float* W2n  = (const float*)d_in[9];
    const float* b2   = (const float*)d_in[10];
    const float* Wfc  = (const float*)d_in[11];
    const float* bfc  = (const float*)d_in[12];
    float* out = (float*)d_out;

    char* ws = (char*)d_ws;
    size_t o = 0;
    // --- zeroed region (single contiguous memset, ~467 KB) ---
    size_t off_cnt    = o; o += 256;                            // [0]=L1 count, [1]=257
    size_t off_flagL2 = o; o += ((size_t)NN * 4 + 255) / 256 * 256;
    size_t off_flagL1 = o; o += ((size_t)NN * 4 + 255) / 256 * 256;
    size_t off_cur1   = o; o += (size_t)L1CAP * 4;              // doubles as deg1
    size_t off_cur2   = o; o += (size_t)L2CAP * 4;              // doubles as deg2
    size_t zero_bytes = o;
    // --- non-zeroed ---
    size_t off_nodeL2 = o; o += (size_t)L2CAP * 4;
    size_t off_nodeL1 = o; o += (size_t)L1CAP * 4;
    size_t off_bsrc1  = o; o += (size_t)L1CAP * BCAP * 4;       // 4 MB
    size_t off_bsrc2  = o; o += (size_t)L2CAP * BCAP * 4;       // 128 KB
    size_t off_agg1c  = o; o += (size_t)L1CAP * FD * 4;         // 8 MB
    size_t off_agg2c  = o; o += (size_t)L2CAP * FD * 4;
    size_t off_h1c    = o; o += (size_t)L1CAP * FD * 4;         // 8 MB
    size_t off_h2c    = o; o += (size_t)L2CAP * FD * 4;

    int*   cnt    = (int*)(ws + off_cnt);
    int*   flagL2 = (int*)(ws + off_flagL2);
    int*   flagL1 = (int*)(ws + off_flagL1);
    int*   cur1   = (int*)(ws + off_cur1);
    int*   cur2   = (int*)(ws + off_cur2);
    int*   nodeL2 = (int*)(ws + off_nodeL2);
    int*   nodeL1 = (int*)(ws + off_nodeL1);
    int*   bsrc1  = (int*)(ws + off_bsrc1);
    int*   bsrc2  = (int*)(ws + off_bsrc2);
    float* agg1c  = (float*)(ws + off_agg1c);
    float* agg2c  = (float*)(ws + off_agg2c);
    float* h1c    = (float*)(ws + off_h1c);
    float* h2c    = (float*)(ws + off_h2c);

    hipMemsetAsync(ws, 0, zero_bytes, stream);

    k_mark<<<1, 320, 0, stream>>>(states, acts, flagL2, flagL1, nodeL2, cnt);
    k_scan_targets<<<(NE / 4 + 255) / 256, 256, 0, stream>>>(
        (const int4*)esrc, (const int4*)edst, flagL2, flagL1, cur2, bsrc2);
    k_assign<<<(NN + 255) / 256, 256, 0, stream>>>(flagL1, nodeL1, cnt);
    k_scan_l1<<<(NE / 4 + 255) / 256, 256, 0, stream>>>(
        (const int4*)esrc, (const int4*)edst, flagL1, cur1, bsrc1);

    // layer 1: wave-per-slot gather -> agg1c, then GEMM -> h1c
    k_gather<<<L1CAP / 4, 256, 0, stream>>>(cur1, bsrc1, nullptr, cnt + 0, x, agg1c);
    k_gemm<<<L1CAP / GSLOTS, 256, 0, stream>>>(
        x, nodeL1, nullptr, agg1c, cur1, W1s, W1n, b1, h1c, cnt + 0);
    // layer 2: gather maps raw ids -> h1c rows via flagL1; self row likewise
    k_gather<<<L2CAP / 4, 256, 0, stream>>>(cur2, bsrc2, flagL1, cnt + 1, h1c, agg2c);
    k_gemm<<<L2CAP / GSLOTS, 256, 0, stream>>>(
        h1c, nodeL2, flagL1, agg2c, cur2, W2s, W2n, b2, h2c, cnt + 1);

    k_readout<<<1, 256, 0, stream>>>(h2c, flagL2, states, acts, Wfc, bfc, out);
}

// Round 8
// 213.559 us; speedup vs baseline: 1.3442x; 1.3442x over previous
//
#include <hip/hip_runtime.h>
#include <hip/hip_bf16.h>

#define NN 50000
#define NE 800000
#define FD 128
#define L1CAP 16000
#define L2CAP 512
#define BCAP 64      // per-slot bucket capacity; mean in-degree 16, P(>64) ~ 1e-18

// ---------------- frontier construction ----------------

__global__ void k_mark(const int* __restrict__ states, const int* __restrict__ actions,
                       int* __restrict__ flagL2, int* __restrict__ flagL1,
                       int* __restrict__ nodeL2, int* __restrict__ cnt) {
    int i = blockIdx.x * blockDim.x + threadIdx.x;
    if (i == 0) cnt[1] = 257;   // fixed layer-2 slot count
    if (i < 257) {
        int n = (i < 256) ? states[i] : actions[0];
        flagL2[n] = i + 1;      // duplicate states race: one slot wins; losing slots
        flagL1[n] = 1;          // are never read (readout maps through flagL2)
        nodeL2[i] = n;
    }
}

// Scan all edges for layer-2 targets; bucket hits directly (fixed stride).
__global__ __launch_bounds__(256) void k_scan_targets(
        const int4* __restrict__ esrc4, const int4* __restrict__ edst4,
        const int* __restrict__ flagL2, int* __restrict__ flagL1,
        int* __restrict__ cur2, int* __restrict__ bsrc2) {
    int t = blockIdx.x * blockDim.x + threadIdx.x;
    if (t >= NE / 4) return;
    int4 d4 = edst4[t];
    int4 s4 = esrc4[t];
    int f[4] = {flagL2[d4.x], flagL2[d4.y], flagL2[d4.z], flagL2[d4.w]};
    int s[4] = {s4.x, s4.y, s4.z, s4.w};
#pragma unroll
    for (int j = 0; j < 4; ++j) {
        if (f[j] > 0) {
            int slot = f[j] - 1;
            int pos = atomicAdd(&cur2[slot], 1);
            if (pos < BCAP) bsrc2[slot * BCAP + pos] = s[j];  // raw node id
            flagL1[s[j]] = 1;   // idempotent mark
        }
    }
}

// Compact L1 frontier: flagL1[n] -> slot+1, nodeL1[slot] = n.
__global__ __launch_bounds__(256) void k_assign(
        int* __restrict__ flagL1, int* __restrict__ nodeL1, int* __restrict__ cnt) {
    int n = blockIdx.x * blockDim.x + threadIdx.x;
    bool pred = (n < NN) && (flagL1[n] != 0);
    unsigned long long mask = __ballot(pred);
    if (mask == 0) return;
    int lane = threadIdx.x & 63;
    int prefix = __popcll(mask & ((1ull << lane) - 1));
    int fl = __ffsll((long long)mask) - 1;
    int base = 0;
    if (lane == fl) base = atomicAdd(&cnt[0], __popcll(mask));
    base = __shfl(base, fl, 64);
    if (pred) {
        int slot = base + prefix;
        if (slot < L1CAP) { flagL1[n] = slot + 1; nodeL1[slot] = n; }
        else flagL1[n] = 0;     // overflow safety (never hit with this graph)
    }
}

// Scan all edges for L1-frontier destinations; bucket hits (fixed stride).
__global__ __launch_bounds__(256) void k_scan_l1(
        const int4* __restrict__ esrc4, const int4* __restrict__ edst4,
        const int* __restrict__ flagL1, int* __restrict__ cur1,
        int* __restrict__ bsrc1) {
    int t = blockIdx.x * blockDim.x + threadIdx.x;
    if (t >= NE / 4) return;
    int4 d4 = edst4[t];
    int4 s4 = esrc4[t];
    int f[4] = {flagL1[d4.x], flagL1[d4.y], flagL1[d4.z], flagL1[d4.w]};
    int s[4] = {s4.x, s4.y, s4.z, s4.w};
#pragma unroll
    for (int j = 0; j < 4; ++j) {
        if (f[j] > 0) {
            int slot = f[j] - 1;
            int pos = atomicAdd(&cur1[slot], 1);
            if (pos < BCAP) bsrc1[slot * BCAP + pos] = s[j];  // x row id
        }
    }
}

// ---------------- aggregation gather (1 wave per slot, zero atomics) --------

__global__ __launch_bounds__(256) void k_gather(
        const int* __restrict__ cur, const int* __restrict__ bsrc,
        const int* __restrict__ srcMap, const int* __restrict__ cntPtr,
        const float* __restrict__ srcMat, float* __restrict__ aggc) {
    int w = (blockIdx.x * blockDim.x + threadIdx.x) >> 6;
    int lane = threadIdx.x & 63;
    if (w >= *cntPtr) return;
    int n = cur[w]; if (n > BCAP) n = BCAP;
    const int* bp = bsrc + (size_t)w * BCAP;
    float ax = 0.0f, ay = 0.0f;
    int e = 0;
    for (; e + 1 < n; e += 2) {       // 2-edge unroll for load ILP
        int r0 = bp[e], r1 = bp[e + 1];
        if (srcMap) { r0 = srcMap[r0] - 1; r1 = srcMap[r1] - 1; }
        float2 v0 = ((const float2*)(srcMat + (size_t)r0 * FD))[lane];
        float2 v1 = ((const float2*)(srcMat + (size_t)r1 * FD))[lane];
        ax += v0.x + v1.x; ay += v0.y + v1.y;
    }
    if (e < n) {
        int r = bp[e];
        if (srcMap) r = srcMap[r] - 1;
        float2 v = ((const float2*)(srcMat + (size_t)r * FD))[lane];
        ax += v.x; ay += v.y;
    }
    float2 outv = {ax, ay};
    ((float2*)(aggc + (size_t)w * FD))[lane] = outv;
}

// ---------------- fused SAGE layer GEMM ----------------
// out[slot][o] = relu( self·Wself[o] + (agg/max(deg,1))·Wneigh[o] + b[o] )
// block = 256 thr (4 waves), tile 32 slots x 128 outs, micro 2x8.
// KEY: W is staged through LDS in 16-col chunks. Previous versions streamed
// W from global inside the K-loop; at VGPR=64 the compiler kept only ~2-4
// loads in flight -> per-wave serialized L2 round-trips -> 61 us walls
// invariant to grid size (9-block layer-2 == 138-block layer-1). LDS staging
// pays latency once per chunk via 4 independent coalesced loads/thread.
// Strides: sx/sa 132, swS/swN 20 (both mult-of-4 -> 16B-aligned b128 reads;
// bank aliasing <= 2-way = free).

#define GSLOTS 32
#define LDSTR 132
#define WCH 16
#define WSTR 20

__global__ __launch_bounds__(256, 2) void k_gemm(
        const float* __restrict__ selfMat, const int* __restrict__ selfIdx,
        const int* __restrict__ selfMap, const float* __restrict__ aggc,
        const int* __restrict__ cur,
        const float* __restrict__ Wself, const float* __restrict__ Wneigh,
        const float* __restrict__ bias, float* __restrict__ outc,
        const int* __restrict__ cntPtr) {
    __shared__ float sx[GSLOTS][LDSTR];
    __shared__ float sa[GSLOTS][LDSTR];
    __shared__ float swS[FD][WSTR];
    __shared__ float swN[FD][WSTR];
    __shared__ int   srowL[GSLOTS];
    __shared__ float sinvL[GSLOTS];
    int cnt = *cntPtr;
    int base = blockIdx.x * GSLOTS;
    if (base >= cnt) return;
    int tid = threadIdx.x;

    // phase A: resolve slot indices & degree factors (parallel, one chain)
    if (tid < GSLOTS) {
        int slot = base + tid;
        bool live = slot < cnt;
        int sidx = live ? selfIdx[slot] : 0;
        int srow = selfMap ? (selfMap[sidx] - 1) : sidx;
        if (srow < 0) srow = 0;                    // dead-slot safety
        srowL[tid] = srow;
        int n = live ? cur[slot] : 0;
        sinvL[tid] = 1.0f / fmaxf((float)n, 1.0f);
    }
    __syncthreads();

    // phase B: batched vector staging. 256 thr x float4 = 8 rows/pass, 4 passes.
    {
        int c4 = tid & 31;          // float4 column 0..31
        int r0 = tid >> 5;          // row 0..7
        float4 rx[4], ra[4];
#pragma unroll
        for (int i = 0; i < 4; ++i) {
            int r = r0 + 8 * i;
            int sr = srowL[r];
            rx[i] = ((const float4*)(selfMat + (size_t)sr * FD))[c4];
            ra[i] = ((const float4*)(aggc + (size_t)(base + r) * FD))[c4];
        }
#pragma unroll
        for (int i = 0; i < 4; ++i) {
            int r = r0 + 8 * i;
            float inv = sinvL[r];
            *(float4*)&sx[r][c4 * 4] = rx[i];
            float4 a = ra[i];
            a.x *= inv; a.y *= inv; a.z *= inv; a.w *= inv;
            *(float4*)&sa[r][c4 * 4] = a;
        }
    }
    __syncthreads();

    int og = tid & 15;       // 16 out-groups -> o = og + 16*j
    int sg = tid >> 4;       // 16 slot-groups -> s = sg + 16*i
    float acc[2][8];
#pragma unroll
    for (int i = 0; i < 2; ++i)
#pragma unroll
        for (int j = 0; j < 8; ++j) acc[i][j] = 0.0f;

    for (int kb = 0; kb < FD; kb += WCH) {
        // stage W chunk: 512 float4 per matrix, 2 per thread per matrix,
        // all 4 loads independent & coalesced.
#pragma unroll
        for (int i = 0; i < 2; ++i) {
            int idx = tid + 256 * i;            // 0..511
            int o = idx >> 2, c4 = (idx & 3) * 4;
            float4 vs = *(const float4*)(Wself + (size_t)o * FD + kb + c4);
            float4 vn = *(const float4*)(Wneigh + (size_t)o * FD + kb + c4);
            *(float4*)&swS[o][c4] = vs;
            *(float4*)&swN[o][c4] = vn;
        }
        __syncthreads();

#pragma unroll
        for (int k = 0; k < WCH; k += 4) {
            float4 xv[2], av[2];
#pragma unroll
            for (int i = 0; i < 2; ++i) {
                int s = sg + 16 * i;
                xv[i] = *(const float4*)&sx[s][kb + k];
                av[i] = *(const float4*)&sa[s][kb + k];
            }
#pragma unroll
            for (int j = 0; j < 8; ++j) {
                int o = og + 16 * j;
                float4 ws = *(const float4*)&swS[o][k];
                float4 wn = *(const float4*)&swN[o][k];
#pragma unroll
                for (int i = 0; i < 2; ++i) {
                    acc[i][j] += xv[i].x * ws.x + xv[i].y * ws.y + xv[i].z * ws.z + xv[i].w * ws.w
                               + av[i].x * wn.x + av[i].y * wn.y + av[i].z * wn.z + av[i].w * wn.w;
                }
            }
        }
        __syncthreads();
    }

#pragma unroll
    for (int j = 0; j < 8; ++j) {
        int o = og + 16 * j;
        float b = bias[o];
#pragma unroll
        for (int i = 0; i < 2; ++i) {
            int slot = base + sg + 16 * i;
            outc[(size_t)slot * FD + o] = fmaxf(acc[i][j] + b, 0.0f);
        }
    }
}

// ---------------- readout ----------------
// Transposed: thread owns one feature, register fmax chain, zero atomics.

__global__ __launch_bounds__(256) void k_readout(
        const float* __restrict__ h2c, const int* __restrict__ flagL2,
        const int* __restrict__ states, const int* __restrict__ actions,
        const float* __restrict__ Wfc, const float* __restrict__ bfc,
        float* __restrict__ out) {
    __shared__ int slotS[256];
    __shared__ float halfmax[2][FD];
    __shared__ float red[256];
    int tid = threadIdx.x;
    slotS[tid] = flagL2[states[tid]] - 1;
    __syncthreads();

    int f = tid & (FD - 1);
    int half = tid >> 7;             // 0 or 1
    float m = 0.0f;                  // h2 >= 0 post-ReLU, 0 is identity for max
#pragma unroll 8
    for (int s = half * 128; s < half * 128 + 128; ++s) {
        m = fmaxf(m, h2c[(size_t)slotS[s] * FD + f]);
    }
    halfmax[half][f] = m;
    __syncthreads();

    float v = 0.0f;
    if (tid < FD) {
        int aslot = flagL2[actions[0]] - 1;
        float mm = fmaxf(halfmax[0][tid], halfmax[1][tid]);
        float av = h2c[(size_t)aslot * FD + tid];
        v = mm * Wfc[tid] + av * Wfc[FD + tid];
    }
    red[tid] = v;
    __syncthreads();
    for (int s = 128; s > 0; s >>= 1) {
        if (tid < s) red[tid] += red[tid + s];
        __syncthreads();
    }
    if (tid == 0) out[0] = red[0] + bfc[0];
}

// ---------------- launch ----------------

extern "C" void kernel_launch(void* const* d_in, const int* in_sizes, int n_in,
                              void* d_out, int out_size, void* d_ws, size_t ws_size,
                              hipStream_t stream) {
    const float* x    = (const float*)d_in[0];
    const int* esrc   = (const int*)d_in[1];
    const int* edst   = (const int*)d_in[2];
    const int* states = (const int*)d_in[3];
    const int* acts   = (const int*)d_in[4];
    const float* W1s  = (const float*)d_in[5];
    const float* W1n  = (const float*)d_in[6];
    const float* b1   = (const float*)d_in[7];
    const float* W2s  = (const float*)d_in[8];
    const float* W2n  = (const float*)d_in[9];
    const float* b2   = (const float*)d_in[10];
    const float* Wfc  = (const float*)d_in[11];
    const float* bfc  = (const float*)d_in[12];
    float* out = (float*)d_out;

    char* ws = (char*)d_ws;
    size_t o = 0;
    // --- zeroed region (single contiguous memset, ~467 KB) ---
    size_t off_cnt    = o; o += 256;                            // [0]=L1 count, [1]=257
    size_t off_flagL2 = o; o += ((size_t)NN * 4 + 255) / 256 * 256;
    size_t off_flagL1 = o; o += ((size_t)NN * 4 + 255) / 256 * 256;
    size_t off_cur1   = o; o += (size_t)L1CAP * 4;              // doubles as deg1
    size_t off_cur2   = o; o += (size_t)L2CAP * 4;              // doubles as deg2
    size_t zero_bytes = o;
    // --- non-zeroed ---
    size_t off_nodeL2 = o; o += (size_t)L2CAP * 4;
    size_t off_nodeL1 = o; o += (size_t)L1CAP * 4;
    size_t off_bsrc1  = o; o += (size_t)L1CAP * BCAP * 4;       // 4 MB
    size_t off_bsrc2  = o; o += (size_t)L2CAP * BCAP * 4;       // 128 KB
    size_t off_agg1c  = o; o += (size_t)L1CAP * FD * 4;         // 8 MB
    size_t off_agg2c  = o; o += (size_t)L2CAP * FD * 4;
    size_t off_h1c    = o; o += (size_t)L1CAP * FD * 4;         // 8 MB
    size_t off_h2c    = o; o += (size_t)L2CAP * FD * 4;

    int*   cnt    = (int*)(ws + off_cnt);
    int*   flagL2 = (int*)(ws + off_flagL2);
    int*   flagL1 = (int*)(ws + off_flagL1);
    int*   cur1   = (int*)(ws + off_cur1);
    int*   cur2   = (int*)(ws + off_cur2);
    int*   nodeL2 = (int*)(ws + off_nodeL2);
    int*   nodeL1 = (int*)(ws + off_nodeL1);
    int*   bsrc1  = (int*)(ws + off_bsrc1);
    int*   bsrc2  = (int*)(ws + off_bsrc2);
    float* agg1c  = (float*)(ws + off_agg1c);
    float* agg2c  = (float*)(ws + off_agg2c);
    float* h1c    = (float*)(ws + off_h1c);
    float* h2c    = (float*)(ws + off_h2c);

    hipMemsetAsync(ws, 0, zero_bytes, stream);

    k_mark<<<1, 320, 0, stream>>>(states, acts, flagL2, flagL1, nodeL2, cnt);
    k_scan_targets<<<(NE / 4 + 255) / 256, 256, 0, stream>>>(
        (const int4*)esrc, (const int4*)edst, flagL2, flagL1, cur2, bsrc2);
    k_assign<<<(NN + 255) / 256, 256, 0, stream>>>(flagL1, nodeL1, cnt);
    k_scan_l1<<<(NE / 4 + 255) / 256, 256, 0, stream>>>(
        (const int4*)esrc, (const int4*)edst, flagL1, cur1, bsrc1);

    // layer 1: wave-per-slot gather -> agg1c, then GEMM -> h1c
    k_gather<<<L1CAP / 4, 256, 0, stream>>>(cur1, bsrc1, nullptr, cnt + 0, x, agg1c);
    k_gemm<<<L1CAP / GSLOTS, 256, 0, stream>>>(
        x, nodeL1, nullptr, agg1c, cur1, W1s, W1n, b1, h1c, cnt + 0);
    // layer 2: gather maps raw ids -> h1c rows via flagL1; self row likewise
    k_gather<<<L2CAP / 4, 256, 0, stream>>>(cur2, bsrc2, flagL1, cnt + 1, h1c, agg2c);
    k_gemm<<<L2CAP / GSLOTS, 256, 0, stream>>>(
        h1c, nodeL2, flagL1, agg2c, cur2, W2s, W2n, b2, h2c, cnt + 1);

    k_readout<<<1, 256, 0, stream>>>(h2c, flagL2, states, acts, Wfc, bfc, out);
}